// Round 1
// baseline (5184.635 us; speedup 1.0000x reference)
//
#include <hip/hip_runtime.h>
#include <math.h>

#define B_ 8
#define C_ 512
#define W_ 64
#define H_ 32
#define HID_ 256
#define G_ 1280
#define WH_ (W_*H_)          // 2048
#define CELL_STRIDE (B_*HID_) // 2048 floats per (w,h) cell in hbuf/cbuf

// LDS row strides padded to break 8-way bank conflicts (stride%32==4, 16B aligned)
#define HL_STRIDE 260
#define XS_STRIDE 516
#define GB_STRIDE 68

__device__ __forceinline__ float sigmoidf_(float x) {
    return 1.0f / (1.0f + __expf(-x));
}

__device__ __forceinline__ float tanhf_(float x) {
    // overflow-safe: exp of negative argument only
    float ax = fabsf(x);
    float e = __expf(-2.0f * ax);
    float t = (1.0f - e) / (1.0f + e);
    return copysignf(t, x);
}

// ---------------------------------------------------------------------------
// A0: transpose x (B,C,W,H) = [bc][wh] row-major  ->  xT [wh][bc]
// ---------------------------------------------------------------------------
__global__ __launch_bounds__(256) void k_transpose_x(const float* __restrict__ x,
                                                     float* __restrict__ xT) {
    __shared__ float tile[64][65];
    int bc0 = blockIdx.x * 64;   // 4096/64 = 64 tiles
    int wh0 = blockIdx.y * 64;   // 2048/64 = 32 tiles
    int xcol = threadIdx.x & 63;
    int yrow = threadIdx.x >> 6;
    for (int yy = yrow; yy < 64; yy += 4)
        tile[yy][xcol] = x[(size_t)(bc0 + yy) * WH_ + wh0 + xcol];
    __syncthreads();
    for (int yy = yrow; yy < 64; yy += 4)
        xT[(size_t)(wh0 + yy) * (B_*C_) + bc0 + xcol] = tile[xcol][yy];
}

// ---------------------------------------------------------------------------
// A: xp[wh][b][g] = sum_c xT[wh][b][c] * Wx[c][g] + bias[g]
// grid = WH*4 (n-tiles of 64), block = 640 (10 waves)
// ---------------------------------------------------------------------------
__global__ __launch_bounds__(640) void k_xproj(const float* __restrict__ xT,
                                               const float* __restrict__ Wx,
                                               const float* __restrict__ bias,
                                               float* __restrict__ xp) {
    __shared__ float xs[B_ * XS_STRIDE];
    int wh = blockIdx.x >> 2;
    int n0 = (blockIdx.x & 3) * 64;
    int tid = threadIdx.x;

    // stage x row (8 x 512 floats, contiguous) into padded LDS
    {
        const float4* src = (const float4*)(xT + (size_t)wh * (B_*C_));
        for (int i = tid; i < (B_*C_)/4; i += 640) {
            int row = i >> 7;          // /128 float4 per row
            int c4  = i & 127;
            *(float4*)&xs[row * XS_STRIDE + c4 * 4] = src[i];
        }
    }
    __syncthreads();

    int wv = tid >> 6, lane = tid & 63;
    int gate = wv % 5, half = wv / 5;
    int b = lane >> 3, jg = lane & 7;
    int j = gate * 256 + n0 + half * 32 + jg * 4;

    float4 acc = *(const float4*)(bias + j);
    const float* xrow = xs + b * XS_STRIDE;

    for (int k = 0; k < C_; k += 4) {
        float4 xv = *(const float4*)(xrow + k);
#define XSTEP(r, comp)                                                          \
        {                                                                       \
            float4 wv4 = *(const float4*)(Wx + (size_t)(k + r) * G_ + j);       \
            acc.x += comp * wv4.x; acc.y += comp * wv4.y;                       \
            acc.z += comp * wv4.z; acc.w += comp * wv4.w;                       \
        }
        XSTEP(0, xv.x) XSTEP(1, xv.y) XSTEP(2, xv.z) XSTEP(3, xv.w)
#undef XSTEP
    }
    *(float4*)(xp + ((size_t)wh * B_ + b) * G_ + j) = acc;
}

// ---------------------------------------------------------------------------
// B: one anti-diagonal step. grid = n_d*4, block = 640.
// g = xp + h_left @ Wh1 + h_up @ Wh2 ; gates ; c,h update.
// ---------------------------------------------------------------------------
__global__ __launch_bounds__(640) void k_diag(const float* __restrict__ xp,
                                              const float* __restrict__ Wh1,
                                              const float* __restrict__ Wh2,
                                              float* __restrict__ hbuf,
                                              float* __restrict__ cbuf,
                                              int d, int wlo) {
    __shared__ float hl[B_ * HL_STRIDE];
    __shared__ float hu[B_ * HL_STRIDE];
    __shared__ float gb[5][B_][GB_STRIDE];

    int ci = blockIdx.x >> 2;
    int n0 = (blockIdx.x & 3) * 64;
    int w = wlo + ci;
    int h = d - w;
    int wh = w * H_ + h;
    int tid = threadIdx.x;

    // stage h_left (w,h-1) and h_up (w-1,h); zeros at boundaries
    {
        const float4* sl = (h > 0) ? (const float4*)(hbuf + (size_t)(wh - 1) * CELL_STRIDE) : nullptr;
        const float4* su = (w > 0) ? (const float4*)(hbuf + (size_t)(wh - H_) * CELL_STRIDE) : nullptr;
        float4 z; z.x = z.y = z.z = z.w = 0.f;
        if (tid < 512) {
            int row = tid >> 6;   // 64 float4 per 256-float row
            int c4  = tid & 63;
            *(float4*)&hl[row * HL_STRIDE + c4 * 4] = sl ? sl[tid] : z;
            *(float4*)&hu[row * HL_STRIDE + c4 * 4] = su ? su[tid] : z;
        }
    }
    __syncthreads();

    int wv = tid >> 6, lane = tid & 63;
    int gate = wv % 5, half = wv / 5;
    int b = lane >> 3, jg = lane & 7;
    int j = gate * 256 + n0 + half * 32 + jg * 4;

    float4 acc = *(const float4*)(xp + ((size_t)wh * B_ + b) * G_ + j);
    const float* hlr = hl + b * HL_STRIDE;
    const float* hur = hu + b * HL_STRIDE;

    for (int k = 0; k < HID_; k += 4) {
        float4 a4 = *(const float4*)(hlr + k);
        float4 u4 = *(const float4*)(hur + k);
#define DSTEP(r, ac, uc)                                                        \
        {                                                                       \
            float4 w1 = *(const float4*)(Wh1 + (size_t)(k + r) * G_ + j);       \
            float4 w2 = *(const float4*)(Wh2 + (size_t)(k + r) * G_ + j);       \
            acc.x += ac * w1.x + uc * w2.x;                                     \
            acc.y += ac * w1.y + uc * w2.y;                                     \
            acc.z += ac * w1.z + uc * w2.z;                                     \
            acc.w += ac * w1.w + uc * w2.w;                                     \
        }
        DSTEP(0, a4.x, u4.x) DSTEP(1, a4.y, u4.y)
        DSTEP(2, a4.z, u4.z) DSTEP(3, a4.w, u4.w)
#undef DSTEP
    }

    *(float4*)&gb[gate][b][half * 32 + jg * 4] = acc;
    __syncthreads();

    if (tid < 512) {
        int b2 = tid >> 6, nn = tid & 63;
        int n = n0 + nn;
        float iv = sigmoidf_(gb[0][b2][nn]);
        float f1 = sigmoidf_(gb[1][b2][nn]);
        float f2 = sigmoidf_(gb[2][b2][nn]);
        float ov = sigmoidf_(gb[3][b2][nn]);
        float cd = tanhf_(gb[4][b2][nn]);
        float cl = (h > 0) ? cbuf[(size_t)(wh - 1) * CELL_STRIDE + b2 * HID_ + n] : 0.f;
        float cu = (w > 0) ? cbuf[(size_t)(wh - H_) * CELL_STRIDE + b2 * HID_ + n] : 0.f;
        float c = iv * cd + f1 * cl + f2 * cu;
        float hh = ov * tanhf_(c);
        cbuf[(size_t)wh * CELL_STRIDE + b2 * HID_ + n] = c;
        hbuf[(size_t)wh * CELL_STRIDE + b2 * HID_ + n] = hh;
    }
}

// ---------------------------------------------------------------------------
// C1: BN partial stats. hbuf viewed as (16384 rows x 256 cols); column sums.
// ---------------------------------------------------------------------------
__global__ __launch_bounds__(256) void k_stats(const float* __restrict__ hbuf,
                                               float* __restrict__ ssum,
                                               float* __restrict__ ssq) {
    int t = threadIdx.x;
    size_t r0 = (size_t)blockIdx.x * 64;
    float s = 0.f, q = 0.f;
    for (int r = 0; r < 64; ++r) {
        float v = hbuf[(r0 + r) * HID_ + t];
        s += v; q += v * v;
    }
    atomicAdd(&ssum[t], s);
    atomicAdd(&ssq[t], q);
}

__global__ void k_finstats(const float* __restrict__ ssum, const float* __restrict__ ssq,
                           float* __restrict__ mean, float* __restrict__ rinv) {
    int t = threadIdx.x;
    const float inv_n = 1.0f / 16384.0f;
    float m = ssum[t] * inv_n;
    float v = ssq[t] * inv_n - m * m;
    mean[t] = m;
    rinv[t] = rsqrtf(v + 1e-5f);
}

// ---------------------------------------------------------------------------
// C2: transpose (wh,b,n) -> (b,n,wh) for state & cell, fused BN+tanh for out.
// grid = 8 * 32 * 4, block = 256. 64x64 LDS tile per pass.
// ---------------------------------------------------------------------------
__global__ __launch_bounds__(256) void k_out(const float* __restrict__ hbuf,
                                             const float* __restrict__ cbuf,
                                             const float* __restrict__ mean,
                                             const float* __restrict__ rinv,
                                             const float* __restrict__ gamma,
                                             const float* __restrict__ beta,
                                             float* __restrict__ outp) {
    __shared__ float tile[64][65];
    int bi = blockIdx.x;
    int b = bi >> 7;
    int rem = bi & 127;
    int wh0 = (rem >> 2) * 64;
    int n0 = (rem & 3) * 64;
    int xcol = threadIdx.x & 63;
    int yrow = threadIdx.x >> 6;

    float* out0   = outp;
    float* state0 = outp + (size_t)B_ * HID_ * WH_;
    float* cell0  = state0 + (size_t)B_ * HID_ * WH_;

    // pass 1: state (+ fused BN/tanh out)
    for (int yy = yrow; yy < 64; yy += 4)
        tile[yy][xcol] = hbuf[((size_t)(wh0 + yy) * B_ + b) * HID_ + n0 + xcol];
    __syncthreads();
    for (int yy = yrow; yy < 64; yy += 4) {
        int n = n0 + yy;
        float sv = tile[xcol][yy];
        size_t oidx = ((size_t)b * HID_ + n) * WH_ + wh0 + xcol;
        state0[oidx] = sv;
        float xn = (sv - mean[n]) * rinv[n];
        out0[oidx] = tanhf_(xn * gamma[n] + beta[n]);
    }
    __syncthreads();

    // pass 2: cell
    for (int yy = yrow; yy < 64; yy += 4)
        tile[yy][xcol] = cbuf[((size_t)(wh0 + yy) * B_ + b) * HID_ + n0 + xcol];
    __syncthreads();
    for (int yy = yrow; yy < 64; yy += 4) {
        int n = n0 + yy;
        size_t oidx = ((size_t)b * HID_ + n) * WH_ + wh0 + xcol;
        cell0[oidx] = tile[xcol][yy];
    }
}

// ---------------------------------------------------------------------------
extern "C" void kernel_launch(void* const* d_in, const int* in_sizes, int n_in,
                              void* d_out, int out_size, void* d_ws, size_t ws_size,
                              hipStream_t stream) {
    const float* x     = (const float*)d_in[0];
    const float* Wx    = (const float*)d_in[1];
    const float* Wh1   = (const float*)d_in[2];
    const float* Wh2   = (const float*)d_in[3];
    const float* bias  = (const float*)d_in[4];
    const float* gamma = (const float*)d_in[5];
    const float* beta  = (const float*)d_in[6];
    float* out = (float*)d_out;
    float* ws  = (float*)d_ws;

    // ws layout (floats):
    //   xp   : [0, 20971520)                       83.9 MB
    //   xT   : [20971520, 29360128)                33.5 MB  (dead after k_xproj)
    //   hbuf : aliases xT        [20971520, +4194304)
    //   cbuf : aliases xT+4.2M   [25165824, +4194304)
    //   stats: [29360128, +1024)
    float* xp   = ws;
    float* xT   = ws + 20971520;
    float* hbuf = xT;
    float* cbuf = xT + 4194304;
    float* ssum = ws + 29360128;
    float* ssq  = ssum + 256;
    float* mean = ssum + 512;
    float* rinv = ssum + 768;

    k_transpose_x<<<dim3(64, 32), 256, 0, stream>>>(x, xT);
    k_xproj<<<WH_ * 4, 640, 0, stream>>>(xT, Wx, bias, xp);

    for (int d = 0; d < W_ + H_ - 1; ++d) {
        int wlo = (d - (H_ - 1) > 0) ? d - (H_ - 1) : 0;
        int whi = (d < W_ - 1) ? d : W_ - 1;
        int nd = whi - wlo + 1;
        k_diag<<<nd * 4, 640, 0, stream>>>(xp, Wh1, Wh2, hbuf, cbuf, d, wlo);
    }

    hipMemsetAsync(ssum, 0, 512 * sizeof(float), stream);
    k_stats<<<256, 256, 0, stream>>>(hbuf, ssum, ssq);
    k_finstats<<<1, 256, 0, stream>>>(ssum, ssq, mean, rinv);
    k_out<<<8 * 32 * 4, 256, 0, stream>>>(hbuf, cbuf, mean, rinv, gamma, beta, out);
}

// Round 2
// 1843.142 us; speedup vs baseline: 2.8129x; 2.8129x over previous
//
#include <hip/hip_runtime.h>
#include <math.h>

#define B_ 8
#define C_ 512
#define W_ 64
#define H_ 32
#define HID_ 256
#define G_ 1280
#define WH_ (W_*H_)           // 2048
#define CELL_STRIDE (B_*HID_) // 2048 floats per (w,h) cell in hbuf/cbuf

__device__ __forceinline__ float sigmoidf_(float x) {
    return 1.0f / (1.0f + __expf(-x));
}

__device__ __forceinline__ float tanhf_(float x) {
    float ax = fabsf(x);
    float e = __expf(-2.0f * ax);
    float t = (1.0f - e) / (1.0f + e);
    return copysignf(t, x);
}

// ---------------------------------------------------------------------------
// A0: transpose x (B,C,W,H) = [bc][wh] row-major  ->  xT [wh][bc]
// ---------------------------------------------------------------------------
__global__ __launch_bounds__(256) void k_transpose_x(const float* __restrict__ x,
                                                     float* __restrict__ xT) {
    __shared__ float tile[64][65];
    int bc0 = blockIdx.x * 64;
    int wh0 = blockIdx.y * 64;
    int xcol = threadIdx.x & 63;
    int yrow = threadIdx.x >> 6;
    for (int yy = yrow; yy < 64; yy += 4)
        tile[yy][xcol] = x[(size_t)(bc0 + yy) * WH_ + wh0 + xcol];
    __syncthreads();
    for (int yy = yrow; yy < 64; yy += 4)
        xT[(size_t)(wh0 + yy) * (B_*C_) + bc0 + xcol] = tile[xcol][yy];
}

// ---------------------------------------------------------------------------
// A: GEMM  xp[m][g] = sum_c A[m][c]*Wx[c][g] + bias[g],  m = wh*8+b (16384)
// tiles: BM=64, BN=128, BK=32; block 256 threads; micro-tile 4x8.
// ---------------------------------------------------------------------------
#define BM 64
#define BN 128
#define BK 32
#define AS_STRIDE 68    // [k][m] padded
#define BS_STRIDE 132   // [k][n] padded

__global__ __launch_bounds__(256) void k_xproj(const float* __restrict__ xT,
                                               const float* __restrict__ Wx,
                                               const float* __restrict__ bias,
                                               float* __restrict__ xp) {
    __shared__ float As[BK * AS_STRIDE];
    __shared__ float Bs[BK * BS_STRIDE];

    int mt = blockIdx.x & 255;       // 16384/64 = 256 m-tiles
    int nt = blockIdx.x >> 8;        // 1280/128 = 10 n-tiles
    int m0 = mt * BM, n0 = nt * BN;
    int tid = threadIdx.x;

    int tm = (tid & 15) * 4;         // 0..60
    int tn = (tid >> 4) * 8;         // 0..120

    float acc[4][8];
#pragma unroll
    for (int i = 0; i < 4; ++i)
#pragma unroll
        for (int j = 0; j < 8; ++j) acc[i][j] = 0.f;

    int ar = tid >> 2, aq = tid & 3;   // A staging: row 0..63, float4 idx
    int br = tid >> 3, bq = tid & 7;   // B staging: row 0..31, float4 idx

    for (int kc = 0; kc < C_; kc += BK) {
        float4 av0 = *(const float4*)(xT + (size_t)(m0 + ar) * C_ + kc + aq * 4);
        float4 av1 = *(const float4*)(xT + (size_t)(m0 + ar) * C_ + kc + (aq + 4) * 4);
        float4 bv[4];
#pragma unroll
        for (int s = 0; s < 4; ++s)
            bv[s] = *(const float4*)(Wx + (size_t)(kc + br) * G_ + n0 + (bq + 8 * s) * 4);

        __syncthreads();
        As[(aq * 4 + 0) * AS_STRIDE + ar] = av0.x;
        As[(aq * 4 + 1) * AS_STRIDE + ar] = av0.y;
        As[(aq * 4 + 2) * AS_STRIDE + ar] = av0.z;
        As[(aq * 4 + 3) * AS_STRIDE + ar] = av0.w;
        As[((aq + 4) * 4 + 0) * AS_STRIDE + ar] = av1.x;
        As[((aq + 4) * 4 + 1) * AS_STRIDE + ar] = av1.y;
        As[((aq + 4) * 4 + 2) * AS_STRIDE + ar] = av1.z;
        As[((aq + 4) * 4 + 3) * AS_STRIDE + ar] = av1.w;
#pragma unroll
        for (int s = 0; s < 4; ++s)
            *(float4*)&Bs[br * BS_STRIDE + (bq + 8 * s) * 4] = bv[s];
        __syncthreads();

#pragma unroll
        for (int k = 0; k < BK; ++k) {
            float4 a4 = *(const float4*)&As[k * AS_STRIDE + tm];
            float4 b0 = *(const float4*)&Bs[k * BS_STRIDE + tn];
            float4 b1 = *(const float4*)&Bs[k * BS_STRIDE + tn + 4];
            float am[4] = {a4.x, a4.y, a4.z, a4.w};
            float bn[8] = {b0.x, b0.y, b0.z, b0.w, b1.x, b1.y, b1.z, b1.w};
#pragma unroll
            for (int i = 0; i < 4; ++i)
#pragma unroll
                for (int j = 0; j < 8; ++j)
                    acc[i][j] += am[i] * bn[j];
        }
    }

    float4 bb0 = *(const float4*)(bias + n0 + tn);
    float4 bb1 = *(const float4*)(bias + n0 + tn + 4);
#pragma unroll
    for (int i = 0; i < 4; ++i) {
        size_t row = (size_t)(m0 + tm + i);
        float4 o0, o1;
        o0.x = acc[i][0] + bb0.x; o0.y = acc[i][1] + bb0.y;
        o0.z = acc[i][2] + bb0.z; o0.w = acc[i][3] + bb0.w;
        o1.x = acc[i][4] + bb1.x; o1.y = acc[i][5] + bb1.y;
        o1.z = acc[i][6] + bb1.z; o1.w = acc[i][7] + bb1.w;
        *(float4*)(xp + row * G_ + n0 + tn) = o0;
        *(float4*)(xp + row * G_ + n0 + tn + 4) = o1;
    }
}

// ---------------------------------------------------------------------------
// B: one anti-diagonal step. grid = nd*8 (n-tiles of 32), block = 640.
// Thread (kq4 = tid/160, c = tid%160): owns weight column j(c) for combined-K
// quarter kq4 (K = 512 = 256 Wh1 + 256 Wh2), all 8 batches.
// No duplicate weight reads within a wave (64 consecutive j per load).
// ---------------------------------------------------------------------------
#define NT 32        // n per block
#define NC 160       // columns per block = 5*NT
#define GP_STRIDE 12 // [kq][c][b] padded b-dim (16B-aligned rows: 12*4=48)

__global__ __launch_bounds__(640) void k_diag(const float* __restrict__ xp,
                                              const float* __restrict__ Wh1,
                                              const float* __restrict__ Wh2,
                                              float* __restrict__ hbuf,
                                              float* __restrict__ cbuf,
                                              int d, int wlo) {
    __shared__ float hl[B_ * HID_];          // [b][k], 8 KB
    __shared__ float hu[B_ * HID_];          // 8 KB
    __shared__ float gp[4 * NC * GP_STRIDE]; // 30 KB

    int ci = blockIdx.x >> 3;
    int nt = blockIdx.x & 7;
    int n0 = nt * NT;
    int w = wlo + ci;
    int h = d - w;
    int wh = w * H_ + h;
    int tid = threadIdx.x;

    // stage h_left (wh-1) and h_up (wh-H) into LDS; zeros at boundaries
    {
        const float4* sl = (h > 0) ? (const float4*)(hbuf + (size_t)(wh - 1) * CELL_STRIDE) : nullptr;
        const float4* su = (w > 0) ? (const float4*)(hbuf + (size_t)(wh - H_) * CELL_STRIDE) : nullptr;
        float4 z; z.x = z.y = z.z = z.w = 0.f;
        for (int i = tid; i < 512; i += 640) {
            ((float4*)hl)[i] = sl ? sl[i] : z;
            ((float4*)hu)[i] = su ? su[i] : z;
        }
    }
    __syncthreads();

    int kq4 = tid / NC;          // 0..3 combined-K quarter
    int c   = tid % NC;          // 0..159 column index
    int gate = c >> 5, nn = c & 31;
    int j = gate * 256 + n0 + nn;

    const float* Wm = (kq4 < 2) ? Wh1 : Wh2;
    const float* hm = (kq4 < 2) ? hl : hu;   // wave-uniform (no wave mixes both)
    int kk0 = (kq4 & 1) * 128;

    float acc[8];
#pragma unroll
    for (int b = 0; b < 8; ++b) acc[b] = 0.f;

    for (int kk = kk0; kk < kk0 + 128; kk += 4) {
        float w0 = Wm[(size_t)(kk + 0) * G_ + j];
        float w1 = Wm[(size_t)(kk + 1) * G_ + j];
        float w2 = Wm[(size_t)(kk + 2) * G_ + j];
        float w3 = Wm[(size_t)(kk + 3) * G_ + j];
#pragma unroll
        for (int b = 0; b < 8; ++b) {
            float4 hv = *(const float4*)&hm[b * HID_ + kk];  // broadcast read
            acc[b] += hv.x * w0 + hv.y * w1 + hv.z * w2 + hv.w * w3;
        }
    }

    // store partials: gp[(kq4*NC + c)*12 + b]
    {
        float4 p0, p1;
        p0.x = acc[0]; p0.y = acc[1]; p0.z = acc[2]; p0.w = acc[3];
        p1.x = acc[4]; p1.y = acc[5]; p1.z = acc[6]; p1.w = acc[7];
        int base = (kq4 * NC + c) * GP_STRIDE;
        *(float4*)&gp[base] = p0;
        *(float4*)&gp[base + 4] = p1;
    }
    __syncthreads();

    // reduce 4 quarters + xp -> gp[c*12 + b]
    for (int idx = tid; idx < NC * 8; idx += 640) {
        int b = idx / NC;        // lanes: consecutive c, same b -> coalesced xp
        int cc = idx % NC;
        float s = gp[(0 * NC + cc) * GP_STRIDE + b]
                + gp[(1 * NC + cc) * GP_STRIDE + b]
                + gp[(2 * NC + cc) * GP_STRIDE + b]
                + gp[(3 * NC + cc) * GP_STRIDE + b];
        int g2 = cc >> 5, nn2 = cc & 31;
        int jj = g2 * 256 + n0 + nn2;
        s += xp[((size_t)wh * B_ + b) * G_ + jj];
        gp[cc * GP_STRIDE + b] = s;
    }
    __syncthreads();

    // cell update: 8 b x 32 n
    if (tid < 256) {
        int b = tid >> 5, nn2 = tid & 31;
        int n = n0 + nn2;
        float iv = sigmoidf_(gp[(0 * 32 + nn2) * GP_STRIDE + b]);
        float f1 = sigmoidf_(gp[(1 * 32 + nn2) * GP_STRIDE + b]);
        float f2 = sigmoidf_(gp[(2 * 32 + nn2) * GP_STRIDE + b]);
        float ov = sigmoidf_(gp[(3 * 32 + nn2) * GP_STRIDE + b]);
        float cd = tanhf_(gp[(4 * 32 + nn2) * GP_STRIDE + b]);
        float cl = (h > 0) ? cbuf[(size_t)(wh - 1) * CELL_STRIDE + b * HID_ + n] : 0.f;
        float cu = (w > 0) ? cbuf[(size_t)(wh - H_) * CELL_STRIDE + b * HID_ + n] : 0.f;
        float cv = iv * cd + f1 * cl + f2 * cu;
        float hh = ov * tanhf_(cv);
        cbuf[(size_t)wh * CELL_STRIDE + b * HID_ + n] = cv;
        hbuf[(size_t)wh * CELL_STRIDE + b * HID_ + n] = hh;
    }
}

// ---------------------------------------------------------------------------
// C1: BN partial stats (column sums over 16384 rows x 256 cols)
// ---------------------------------------------------------------------------
__global__ __launch_bounds__(256) void k_stats(const float* __restrict__ hbuf,
                                               float* __restrict__ ssum,
                                               float* __restrict__ ssq) {
    int t = threadIdx.x;
    size_t r0 = (size_t)blockIdx.x * 64;
    float s = 0.f, q = 0.f;
    for (int r = 0; r < 64; ++r) {
        float v = hbuf[(r0 + r) * HID_ + t];
        s += v; q += v * v;
    }
    atomicAdd(&ssum[t], s);
    atomicAdd(&ssq[t], q);
}

__global__ void k_finstats(const float* __restrict__ ssum, const float* __restrict__ ssq,
                           float* __restrict__ mean, float* __restrict__ rinv) {
    int t = threadIdx.x;
    const float inv_n = 1.0f / 16384.0f;
    float m = ssum[t] * inv_n;
    float v = ssq[t] * inv_n - m * m;
    mean[t] = m;
    rinv[t] = rsqrtf(v + 1e-5f);
}

// ---------------------------------------------------------------------------
// C2: transpose (wh,b,n) -> (b,n,wh); fused BN+tanh for out
// ---------------------------------------------------------------------------
__global__ __launch_bounds__(256) void k_out(const float* __restrict__ hbuf,
                                             const float* __restrict__ cbuf,
                                             const float* __restrict__ mean,
                                             const float* __restrict__ rinv,
                                             const float* __restrict__ gamma,
                                             const float* __restrict__ beta,
                                             float* __restrict__ outp) {
    __shared__ float tile[64][65];
    int bi = blockIdx.x;
    int b = bi >> 7;
    int rem = bi & 127;
    int wh0 = (rem >> 2) * 64;
    int n0 = (rem & 3) * 64;
    int xcol = threadIdx.x & 63;
    int yrow = threadIdx.x >> 6;

    float* out0   = outp;
    float* state0 = outp + (size_t)B_ * HID_ * WH_;
    float* cell0  = state0 + (size_t)B_ * HID_ * WH_;

    for (int yy = yrow; yy < 64; yy += 4)
        tile[yy][xcol] = hbuf[((size_t)(wh0 + yy) * B_ + b) * HID_ + n0 + xcol];
    __syncthreads();
    for (int yy = yrow; yy < 64; yy += 4) {
        int n = n0 + yy;
        float sv = tile[xcol][yy];
        size_t oidx = ((size_t)b * HID_ + n) * WH_ + wh0 + xcol;
        state0[oidx] = sv;
        float xn = (sv - mean[n]) * rinv[n];
        out0[oidx] = tanhf_(xn * gamma[n] + beta[n]);
    }
    __syncthreads();

    for (int yy = yrow; yy < 64; yy += 4)
        tile[yy][xcol] = cbuf[((size_t)(wh0 + yy) * B_ + b) * HID_ + n0 + xcol];
    __syncthreads();
    for (int yy = yrow; yy < 64; yy += 4) {
        int n = n0 + yy;
        size_t oidx = ((size_t)b * HID_ + n) * WH_ + wh0 + xcol;
        cell0[oidx] = tile[xcol][yy];
    }
}

// ---------------------------------------------------------------------------
extern "C" void kernel_launch(void* const* d_in, const int* in_sizes, int n_in,
                              void* d_out, int out_size, void* d_ws, size_t ws_size,
                              hipStream_t stream) {
    const float* x     = (const float*)d_in[0];
    const float* Wx    = (const float*)d_in[1];
    const float* Wh1   = (const float*)d_in[2];
    const float* Wh2   = (const float*)d_in[3];
    const float* bias  = (const float*)d_in[4];
    const float* gamma = (const float*)d_in[5];
    const float* beta  = (const float*)d_in[6];
    float* out = (float*)d_out;
    float* ws  = (float*)d_ws;

    float* xp   = ws;                       // 20,971,520 floats
    float* xT   = ws + 20971520;            // 8,388,608 floats (dead after xproj)
    float* hbuf = xT;                       // alias
    float* cbuf = xT + 4194304;             // alias
    float* ssum = ws + 29360128;
    float* ssq  = ssum + 256;
    float* mean = ssum + 512;
    float* rinv = ssum + 768;

    k_transpose_x<<<dim3(64, 32), 256, 0, stream>>>(x, xT);
    k_xproj<<<256 * 10, 256, 0, stream>>>(xT, Wx, bias, xp);

    for (int d = 0; d < W_ + H_ - 1; ++d) {
        int wlo = (d - (H_ - 1) > 0) ? d - (H_ - 1) : 0;
        int whi = (d < W_ - 1) ? d : W_ - 1;
        int nd = whi - wlo + 1;
        k_diag<<<nd * 8, 640, 0, stream>>>(xp, Wh1, Wh2, hbuf, cbuf, d, wlo);
    }

    hipMemsetAsync(ssum, 0, 512 * sizeof(float), stream);
    k_stats<<<256, 256, 0, stream>>>(hbuf, ssum, ssq);
    k_finstats<<<1, 256, 0, stream>>>(ssum, ssq, mean, rinv);
    k_out<<<8 * 32 * 4, 256, 0, stream>>>(hbuf, cbuf, mean, rinv, gamma, beta, out);
}